// Round 11
// baseline (142.656 us; speedup 1.0000x reference)
//
#include <hip/hip_runtime.h>

// MultiHeadAttention: B=8, S=2048, D=256, H=4, hd=64
// R15: attn reverted byte-exact to R12 (best measured 45.7us; R14's 48KB alias
//      bought nothing - grid 512 = 2 blocks/CU is work-limited, occupancy
//      can't rise) + pack_trunc via single v_perm_b32 (bit-identical).
//      qkv: Q/K stores routed through LDS transpose (Bl[1]/Bl[2], chunk-XOR
//      swizzle) -> fully-coalesced dwordx4 global stores (tile rows are
//      contiguous in global since hd=64 spans the full row). Same barriers.
// R12: T4 counted-vmcnt triple-buffer + T5 setprio: attn 49.4->45.7us.
// R8: qkv z-fused (Q,K,V per block), out 128x128 tiles. prep unchanged.
// R6: P-in-register via K-row permutation pi(s)=(s&0x20)|((s&0x0C)<<1)|
//     ((s&0x10)>>2)|(s&3); raw v_exp_f32; fixed-exponent softmax (exact).
// Known fixed costs in dur_us: harness fillBuffer ~46us (workspace zero).
// MFMA layouts (m89/m91 HW-verified):
//   A-frag: lane holds A[m=lane&15][k=(lane>>4)*8+j]
//   B-frag: lane holds B[k=(lane>>4)*8+j][n=lane&15]
//   C/D:    lane,reg holds D[row=(lane>>4)*4+reg][col=lane&15]

typedef unsigned short u16;
typedef __bf16 bf16x8 __attribute__((ext_vector_type(8)));
typedef float  f32x4  __attribute__((ext_vector_type(4)));
typedef unsigned int u32x4 __attribute__((ext_vector_type(4)));
typedef unsigned int u32x2 __attribute__((ext_vector_type(2)));

#define LOG2E   1.4426950408889634f
#define ATTN_SC (0.125f * LOG2E)    // 1/sqrt(64) * log2(e), folded into Q
#define PSTR    2097152             // 16384*128: one K-panel of X / ctx (elements)
#define WPSTR   32768               // 256*128: one K-panel of W^T
#define WZSTR   65536               // per weight matrix (2 panels)

__device__ __forceinline__ u16 f2b(float f) {            // fp32 -> bf16 RNE
  unsigned u = __builtin_bit_cast(unsigned, f);
  u += 0x7FFFu + ((u >> 16) & 1u);
  return (u16)(u >> 16);
}
__device__ __forceinline__ float b2f(u16 b) {
  return __builtin_bit_cast(float, (unsigned)b << 16);
}
// dst = {b[31:16], a[31:16]}: one v_perm_b32 (S0=b -> bytes 4-7, S1=a -> bytes 0-3)
__device__ __forceinline__ unsigned pack_trunc(float a, float b) {
  return __builtin_amdgcn_perm(__builtin_bit_cast(unsigned, b),
                               __builtin_bit_cast(unsigned, a), 0x07060302u);
}
__device__ __forceinline__ unsigned pack_rne(float a, float b) {
  return (unsigned)f2b(a) | ((unsigned)f2b(b) << 16);
}
__device__ __forceinline__ f32x4 mfma16(bf16x8 a, bf16x8 b, f32x4 c) {
  return __builtin_amdgcn_mfma_f32_16x16x32_bf16(a, b, c, 0, 0, 0);
}
// async global->LDS, 16B/lane; LDS dest = wave-uniform base + lane*16
__device__ __forceinline__ void cp16(const u16* g, u16* l) {
  __builtin_amdgcn_global_load_lds((const __attribute__((address_space(1))) void*)g,
                                   (__attribute__((address_space(3))) void*)l, 16, 0, 0);
}

// ---------------- fused prep: x convert + W transpose panel-major ----------------
template <typename T>
__global__ __launch_bounds__(256) void prep(const T* __restrict__ x,
                                            const T* __restrict__ W0, const T* __restrict__ W1,
                                            const T* __restrict__ W2, const T* __restrict__ W3,
                                            const T* __restrict__ b0, const T* __restrict__ b1,
                                            const T* __restrict__ b2, const T* __restrict__ b3,
                                            u16* __restrict__ xp, u16* __restrict__ WTp,
                                            float* __restrict__ biasf) {
  int bid = blockIdx.x;
  if (bid < 4096) {                                      // ---- x: [16384][256] -> panel-major
    int i0 = (bid * 256 + threadIdx.x) * 4;
    int row = i0 >> 8, col = i0 & 255;
    int p = col >> 7, pc = col & 127;
    u16* o = xp + (size_t)p * PSTR + (size_t)row * 128 + pc;
#pragma unroll
    for (int j = 0; j < 4; ++j) {
      if constexpr (sizeof(T) == 4) o[j] = f2b((float)x[i0 + j]);
      else                          o[j] = (u16)x[i0 + j];
    }
  } else {                                               // ---- weights + biases
    bid -= 4096;
    const int z = bid >> 8;
    const T* W = z == 0 ? W0 : z == 1 ? W1 : z == 2 ? W2 : W3;
    const T* b = z == 0 ? b0 : z == 1 ? b1 : z == 2 ? b2 : b3;
    int idx = (bid & 255) * 256 + threadIdx.x;
    int k = idx >> 8, n = idx & 255;
    u16 wb;
    if constexpr (sizeof(T) == 4) wb = f2b((float)W[k * 256 + n]);
    else                          wb = (u16)W[k * 256 + n];
    WTp[z * WZSTR + (k >> 7) * WPSTR + n * 128 + (k & 127)] = wb;
    if (idx < 256) {
      float bv;
      if constexpr (sizeof(T) == 4) bv = (float)b[idx];
      else                          bv = b2f((u16)b[idx]);
      biasf[z * 256 + idx] = bv;
    }
  }
}

// ---------------- QKV projection, z-fused: 128 rows x 64 cols x {Q,K,V} ----------------
// LDS swizzle: logical 16B-chunk c of row r lives at physical chunk c^(r&15).
__global__ __launch_bounds__(256, 2) void qkv_gemm(const u16* __restrict__ xp, const u16* __restrict__ WTp,
                                                   const float* __restrict__ biasf,
                                                   u16* __restrict__ Qw, u16* __restrict__ Kw,
                                                   u16* __restrict__ VTg) {
  __shared__ __align__(16) u16 Al[128 * 128];            // 32 KB
  __shared__ __align__(16) u16 Bl[3][64 * 128];          // 48 KB
  const int tid = threadIdx.x, w = tid >> 6, lane = tid & 63;
  const int l16 = lane & 15, quad = lane >> 4;
  const int n0 = blockIdx.y * 64, m0 = blockIdx.x * 128;
  f32x4 acc[3][2][4];
#pragma unroll
  for (int z = 0; z < 3; ++z)
#pragma unroll
    for (int mm = 0; mm < 2; ++mm)
#pragma unroll
      for (int nb = 0; nb < 4; ++nb) acc[z][mm][nb] = (f32x4){0.f, 0.f, 0.f, 0.f};

#pragma unroll
  for (int p = 0; p < 2; ++p) {
    __syncthreads();
    const u16* Ap = xp + (size_t)m0 * 128 + (size_t)p * PSTR;
#pragma unroll
    for (int i = 0; i < 8; ++i) {                 // A: 128x128 = 2048 chunks
      int slot = i * 256 + w * 64 + lane;
      int row = slot >> 4, pc = slot & 15, c = pc ^ (row & 15);
      cp16(Ap + (size_t)row * 128 + c * 8, Al + (i * 256 + w * 64) * 8);
    }
#pragma unroll
    for (int z = 0; z < 3; ++z) {                 // B[z]: 64x128 = 1024 chunks each
      const u16* Bp = WTp + z * WZSTR + n0 * 128 + p * WPSTR;
#pragma unroll
      for (int i = 0; i < 4; ++i) {
        int slot = i * 256 + w * 64 + lane;
        int row = slot >> 4, pc = slot & 15, c = pc ^ (row & 15);
        cp16(Bp + (size_t)row * 128 + c * 8, Bl[z] + (i * 256 + w * 64) * 8);
      }
    }
    __syncthreads();
#pragma unroll
    for (int kc = 0; kc < 4; ++kc) {
      bf16x8 a0 = *(const bf16x8*)&Al[(w * 32 + l16) * 128 + (((kc * 4 + quad) ^ l16)) * 8];
      bf16x8 a1 = *(const bf16x8*)&Al[(w * 32 + 16 + l16) * 128 + (((kc * 4 + quad) ^ l16)) * 8];
#pragma unroll
      for (int z = 0; z < 3; ++z)
#pragma unroll
        for (int nb = 0; nb < 4; ++nb) {
          bf16x8 b = *(const bf16x8*)&Bl[z][(nb * 16 + l16) * 128 + (((kc * 4 + quad) ^ l16)) * 8];
          acc[z][0][nb] = mfma16(a0, b, acc[z][0][nb]);
          acc[z][1][nb] = mfma16(a1, b, acc[z][1][nb]);
        }
    }
  }

  const int bb = m0 >> 11, s0 = m0 & 2047, h = blockIdx.y;
  __syncthreads();                                 // all compute reads of Bl done
  // ---- stage Q -> Bl[1], K -> Bl[2] as [s][d] tiles (chunk ^ (srow&7) swizzle)
#pragma unroll
  for (int z = 0; z < 2; ++z) {
    const float sc = (z == 0) ? ATTN_SC : 1.0f;
    const float* bp = biasf + z * 256;
    u16* Bz = Bl[1 + z];
#pragma unroll
    for (int mm = 0; mm < 2; ++mm)
#pragma unroll
      for (int nb = 0; nb < 4; ++nb) {
        int d = nb * 16 + l16;
        float bv = bp[n0 + d];
#pragma unroll
        for (int r = 0; r < 4; ++r) {
          int srow = w * 32 + mm * 16 + quad * 4 + r;
          Bz[srow * 64 + (((d >> 3) ^ (srow & 7)) << 3) + (d & 7)] =
              f2b((acc[z][mm][nb][r] + bv) * sc);
        }
      }
  }
  // ---- stage V -> Bl[0] as [d][s] (transpose) tile
  {
    const float* bp = biasf + 2 * 256;
#pragma unroll
    for (int mm = 0; mm < 2; ++mm)
#pragma unroll
      for (int nb = 0; nb < 4; ++nb) {
        int d = nb * 16 + l16;
        float bv = bp[n0 + d];
        f32x4 v = acc[2][mm][nb];
        u32x2 dd = { pack_rne(v[0] + bv, v[1] + bv), pack_rne(v[2] + bv, v[3] + bv) };
        int cch = w * 4 + mm * 2 + (quad >> 1);
        *(u32x2*)&Bl[0][d * 128 + ((cch ^ (d & 15))) * 8 + (quad & 1) * 4] = dd;
      }
  }
  __syncthreads();
  // ---- coalesced stores: Q/K tiles are CONTIGUOUS 16KB blocks in global
  //      (hd=64 spans the full row -> consecutive srow rows adjacent)
#pragma unroll
  for (int i = 0; i < 4; ++i) {
    int slot = i * 256 + tid;
    int srow = slot >> 3, pc = slot & 7;
    u32x4 q4 = *(const u32x4*)&Bl[1][srow * 64 + ((pc ^ (srow & 7)) << 3)];
    *(u32x4*)(Qw + (((size_t)(bb * 4 + h) * 2048) + s0 + srow) * 64 + pc * 8) = q4;
    u32x4 k4 = *(const u32x4*)&Bl[2][srow * 64 + ((pc ^ (srow & 7)) << 3)];
    *(u32x4*)(Kw + (((size_t)(bb * 4 + h) * 2048) + s0 + srow) * 64 + pc * 8) = k4;
  }
#pragma unroll
  for (int i = 0; i < 4; ++i) {
    int slot = i * 256 + tid;
    int d = slot >> 4, pc = slot & 15;
    u32x4 vv = *(const u32x4*)&Bl[0][d * 128 + ((pc ^ (d & 15))) * 8];
    *(u32x4*)(VTg + (((size_t)(bb * 4 + h) * 64) + d) * 2048 + s0 + pc * 8) = vv;
  }
}

// ---------------- output projection: 128 x 128 tiles ----------------
template <bool OUT_BF16>
__global__ __launch_bounds__(256, 2) void out_gemm(const u16* __restrict__ ctxp, const u16* __restrict__ WTp,
                                                   const float* __restrict__ bo, void* __restrict__ outv) {
  __shared__ __align__(16) u16 Al[128 * 128];            // 32 KB
  __shared__ __align__(16) u16 Bl[128 * 128];            // 32 KB
  const int tid = threadIdx.x, w = tid >> 6, lane = tid & 63;
  const int l16 = lane & 15, quad = lane >> 4;
  const int n0 = blockIdx.y * 128, m0 = blockIdx.x * 128;
  f32x4 acc[2][8];
#pragma unroll
  for (int mm = 0; mm < 2; ++mm)
#pragma unroll
    for (int nb = 0; nb < 8; ++nb) acc[mm][nb] = (f32x4){0.f, 0.f, 0.f, 0.f};

#pragma unroll
  for (int p = 0; p < 2; ++p) {
    __syncthreads();
    const u16* Ap = ctxp + (size_t)m0 * 128 + (size_t)p * PSTR;
    const u16* Bp = WTp + 3 * WZSTR + n0 * 128 + p * WPSTR;
#pragma unroll
    for (int i = 0; i < 8; ++i) {                 // A: 128x128 = 2048 chunks
      int slot = i * 256 + w * 64 + lane;
      int row = slot >> 4, pc = slot & 15, c = pc ^ (row & 15);
      cp16(Ap + (size_t)row * 128 + c * 8, Al + (i * 256 + w * 64) * 8);
    }
#pragma unroll
    for (int i = 0; i < 8; ++i) {                 // B: 128x128 = 2048 chunks
      int slot = i * 256 + w * 64 + lane;
      int row = slot >> 4, pc = slot & 15, c = pc ^ (row & 15);
      cp16(Bp + (size_t)row * 128 + c * 8, Bl + (i * 256 + w * 64) * 8);
    }
    __syncthreads();
#pragma unroll
    for (int kc = 0; kc < 4; ++kc) {
      bf16x8 a0 = *(const bf16x8*)&Al[(w * 32 + l16) * 128 + (((kc * 4 + quad) ^ l16)) * 8];
      bf16x8 a1 = *(const bf16x8*)&Al[(w * 32 + 16 + l16) * 128 + (((kc * 4 + quad) ^ l16)) * 8];
#pragma unroll
      for (int nb = 0; nb < 8; ++nb) {
        bf16x8 b = *(const bf16x8*)&Bl[(nb * 16 + l16) * 128 + (((kc * 4 + quad) ^ l16)) * 8];
        acc[0][nb] = mfma16(a0, b, acc[0][nb]);
        acc[1][nb] = mfma16(a1, b, acc[1][nb]);
      }
    }
  }

#pragma unroll
  for (int mm = 0; mm < 2; ++mm)
#pragma unroll
    for (int nb = 0; nb < 8; ++nb) {
      int n = n0 + nb * 16 + l16;
      float bv = bo[n];
#pragma unroll
      for (int r = 0; r < 4; ++r) {
        size_t m = m0 + w * 32 + mm * 16 + quad * 4 + r;
        float v = acc[mm][nb][r] + bv;
        if constexpr (OUT_BF16) ((u16*)outv)[m * 256 + n] = f2b(v);
        else                    ((float*)outv)[m * 256 + n] = v;
      }
    }
}

// ---------------- fused flash attention: counted-vmcnt triple-buffer (R12) ----------------
// grid (16 q-tiles of 128, 32 bh), block 256; wave w owns q rows [q0+32w, +32)
// as two 16-row halves. K rows staged permuted by pi so P stays in-lane.
// Pipeline: STAGE(kt+2) in flight; top-of-loop waits vmcnt(4) = drain only the
// 2-old stage, never the in-flight one (T4). setprio around MFMA (T5).
__global__ __launch_bounds__(256, 2) void attn(const u16* __restrict__ Q, const u16* __restrict__ K,
                                               const u16* __restrict__ VT, u16* __restrict__ ctxp) {
  __shared__ __align__(16) u16 Kt[3][64 * 64];     // [key-slot][d], XOR-swizzled, rows pi-permuted
  __shared__ __align__(16) u16 VTt[3][64 * 64];    // [d][key], natural
  __shared__ __align__(16) u16 Pt[4][16 * 64];     // per-wave epilogue transpose only
  const int tid = threadIdx.x;
  const int w = tid >> 6, lane = tid & 63;
  const int l16 = lane & 15, quad = lane >> 4;
  const int bh = blockIdx.y, q0 = blockIdx.x * 128;
  const u16* Qp = Q + (size_t)bh * 2048 * 64;
  const u16* Kp = K + (size_t)bh * 2048 * 64;
  const u16* Vp = VT + (size_t)bh * 64 * 2048;     // [d][s]
  u16* Ptw = Pt[w];

  bf16x8 qf[2][2];                                 // [half][kc]
#pragma unroll
  for (int h = 0; h < 2; ++h) {
    int qrow = q0 + w * 32 + h * 16 + l16;
    qf[h][0] = *(const bf16x8*)(Qp + (size_t)qrow * 64 + quad * 8);
    qf[h][1] = *(const bf16x8*)(Qp + (size_t)qrow * 64 + 32 + quad * 8);
  }

  f32x4 acc[2][4];                                 // [half][nbD]
#pragma unroll
  for (int h = 0; h < 2; ++h)
#pragma unroll
    for (int nb = 0; nb < 4; ++nb) acc[h][nb] = (f32x4){0.f, 0.f, 0.f, 0.f};
  float dn0 = 0.f, dn1 = 0.f;                      // per-lane denom partials

  // staging geometry: 512 chunk-slots/tensor/tile, 2 per thread; chunk swizzle ^(ldsrow&7)
  const int sl0 = w * 64 + lane, sl1 = 256 + w * 64 + lane;
  const int r0 = sl0 >> 3, c0 = (sl0 & 7) ^ (r0 & 7);
  const int r1 = sl1 >> 3, c1 = (sl1 & 7) ^ (r1 & 7);
  // K row permutation: LDS row s holds global key row pi(s)
  const int pr0 = (r0 & 0x20) | ((r0 & 0x0C) << 1) | ((r0 & 0x10) >> 2) | (r0 & 3);
  const int pr1 = (r1 & 0x20) | ((r1 & 0x0C) << 1) | ((r1 & 0x10) >> 2) | (r1 & 3);

#define STAGE(kt_, KB_, VB_)                                                        \
  do {                                                                              \
    cp16(Kp + (size_t)((kt_) * 64 + pr0) * 64 + c0 * 8, (KB_) + (w * 64) * 8);      \
    cp16(Kp + (size_t)((kt_) * 64 + pr1) * 64 + c1 * 8, (KB_) + (256 + w * 64) * 8);\
    cp16(Vp + (size_t)r0 * 2048 + (kt_) * 64 + c0 * 8, (VB_) + (w * 64) * 8);       \
    cp16(Vp + (size_t)r1 * 2048 + (kt_) * 64 + c1 * 8, (VB_) + (256 + w * 64) * 8); \
  } while (0)

  u16 *Ka = Kt[0], *Kb = Kt[1], *Kc = Kt[2];
  u16 *Va = VTt[0], *Vb = VTt[1], *Vc = VTt[2];
  STAGE(0, Ka, Va);
  STAGE(1, Kb, Vb);

  for (int kt = 0; kt < 32; ++kt) {
    // drain only the stage for THIS tile (issued 2 iterations ago); keep the
    // next stage (4 cp16/thread) in flight across the barrier (T4).
    if (kt == 31) __builtin_amdgcn_s_waitcnt(0x0F70);   // vmcnt(0): last tile
    else          __builtin_amdgcn_s_waitcnt(0x0F74);   // vmcnt(4)
    __asm__ __volatile__("" ::: "memory");
    __builtin_amdgcn_s_barrier();                  // raw barrier: no compiler drain
    __asm__ __volatile__("" ::: "memory");
    if (kt < 30) STAGE(kt + 2, Kc, Vc);            // 2-ahead prefetch

    const u16* KtB = Ka;
    const u16* VtB = Va;

    // hoist K-frags + V-frags once; both q-halves reuse them
    bf16x8 kfr[2][4];                              // [kc][nbK]
#pragma unroll
    for (int kc = 0; kc < 2; ++kc)
#pragma unroll
      for (int nbK = 0; nbK < 4; ++nbK)
        kfr[kc][nbK] = *(const bf16x8*)&KtB[(nbK * 16 + l16) * 64 + (((kc * 4 + quad) ^ (l16 & 7))) * 8];
    bf16x8 vbr[2][4];                              // [m][nbD]
#pragma unroll
    for (int m = 0; m < 2; ++m)
#pragma unroll
      for (int nbD = 0; nbD < 4; ++nbD)
        vbr[m][nbD] = *(const bf16x8*)&VtB[(nbD * 16 + l16) * 64 + (((m * 4 + quad) ^ (l16 & 7))) * 8];

#pragma unroll
    for (int h = 0; h < 2; ++h) {
      // S^T = K * Q^T : lane holds st[key-slot = nbK*16+quad*4+r][q=l16]
      f32x4 st[4];
#pragma unroll
      for (int nb = 0; nb < 4; ++nb) st[nb] = (f32x4){0.f, 0.f, 0.f, 0.f};
      __builtin_amdgcn_s_setprio(1);
#pragma unroll
      for (int kc = 0; kc < 2; ++kc)
#pragma unroll
        for (int nbK = 0; nbK < 4; ++nbK)
          st[nbK] = mfma16(kfr[kc][nbK], qf[h][kc], st[nbK]);
      __builtin_amdgcn_s_setprio(0);

      // P = exp2(st), packed in-lane: thanks to pi, word order IS the PV B-frag
      unsigned pw[8];
      float d = 0.f;
#pragma unroll
      for (int nbK = 0; nbK < 4; ++nbK) {
        float p0 = __builtin_amdgcn_exp2f(st[nbK][0]);
        float p1 = __builtin_amdgcn_exp2f(st[nbK][1]);
        float p2 = __builtin_amdgcn_exp2f(st[nbK][2]);
        float p3 = __builtin_amdgcn_exp2f(st[nbK][3]);
        d += (p0 + p1) + (p2 + p3);
        pw[nbK * 2]     = pack_trunc(p0, p1);
        pw[nbK * 2 + 1] = pack_trunc(p2, p3);
      }
      if (h == 0) dn0 += d; else dn1 += d;
      bf16x8 pb0 = __builtin_bit_cast(bf16x8, (u32x4){pw[0], pw[1], pw[2], pw[3]});
      bf16x8 pb1 = __builtin_bit_cast(bf16x8, (u32x4){pw[4], pw[5], pw[6], pw[7]});

      // ctx^T += V^T * P^T
      __builtin_amdgcn_s_setprio(1);
#pragma unroll
      for (int nbD = 0; nbD < 4; ++nbD) acc[h][nbD] = mfma16(vbr[0][nbD], pb0, acc[h][nbD]);
#pragma unroll
      for (int nbD = 0; nbD < 4; ++nbD) acc[h][nbD] = mfma16(vbr[1][nbD], pb1, acc[h][nbD]);
      __builtin_amdgcn_s_setprio(0);
    }

    // rotate triple buffers (uniform pointer moves)
    u16* t;
    t = Ka; Ka = Kb; Kb = Kc; Kc = t;
    t = Va; Va = Vb; Vb = Vc; Vc = t;
  }
#undef STAGE

  // denom: reduce across the 4 quads sharing q=l16
  float linv0, linv1;
  { float d = dn0; d += __shfl_xor(d, 16); d += __shfl_xor(d, 32); linv0 = 1.0f / d; }
  { float d = dn1; d += __shfl_xor(d, 16); d += __shfl_xor(d, 32); linv1 = 1.0f / d; }

  // epilogue: normalize, transpose via wave-private Ptw, b128 panel-major stores
  const int bb = bh >> 2, hh = bh & 3;
  const int p = hh >> 1, pcol = (hh & 1) * 64;
#pragma unroll
  for (int h = 0; h < 2; ++h) {
    const float linv = h ? linv1 : linv0;
#pragma unroll
    for (int nbD = 0; nbD < 4; ++nbD) {
      f32x4 v = acc[h][nbD];
      u32x2 dd = { pack_rne(v[0] * linv, v[1] * linv), pack_rne(v[2] * linv, v[3] * linv) };
      int cch = nbD * 2 + (quad >> 1);
      *(u32x2*)&Ptw[l16 * 64 + ((cch ^ (l16 & 7))) * 8 + (quad & 1) * 4] = dd;
    }
    __asm__ __volatile__("" ::: "memory");
#pragma unroll
    for (int cc2 = 0; cc2 < 2; ++cc2) {
      int slot = cc2 * 64 + lane;                  // 16 q-rows x 8 chunks
      int row = slot >> 3, pc = slot & 7;
      u32x4 vv = *(const u32x4*)&Ptw[row * 64 + ((pc ^ (row & 7))) * 8];
      size_t m = (size_t)bb * 2048 + q0 + w * 32 + h * 16 + row;
      *(u32x4*)&ctxp[(size_t)p * PSTR + m * 128 + pcol + pc * 8] = vv;
    }
    __asm__ __volatile__("" ::: "memory");
  }
}

// ---------------- host ----------------
extern "C" void kernel_launch(void* const* d_in, const int* in_sizes, int n_in,
                              void* d_out, int out_size, void* d_ws, size_t ws_size,
                              hipStream_t stream) {
  bool f32in = true;
  {
    void* basep = nullptr; size_t sz = 0;
    hipError_t e = hipMemGetAddressRange((hipDeviceptr_t*)&basep, &sz, (hipDeviceptr_t)d_in[0]);
    if (e == hipSuccess && sz > 0) f32in = sz >= (size_t)in_sizes[0] * 4;
    else f32in = false;
  }

  char* ws = (char*)d_ws;
  u16*   xp    = (u16*)(ws + 0);          // 8 MB: X panel-major [2][16384][128]; aliased by ctx after qkv
  u16*   ctxp  = xp;
  u16*   WTp   = (u16*)(ws + 8388608);    // 512 KB: W^T panel-major [4][2][256][128]
  float* biasf = (float*)(ws + 8912896);  // 4 KB
  u16*   Qw    = (u16*)(ws + 8916992);    // 8 MB [B,H,S,hd], pre-scaled by ATTN_SC
  u16*   Kw    = (u16*)(ws + 17305600);   // 8 MB [B,H,S,hd]
  u16*   VTg   = (u16*)(ws + 25694208);   // 8 MB [B,H,hd,S]

  dim3 blk(256);
  if (f32in) {
    prep<float><<<5120, blk, 0, stream>>>(
        (const float*)d_in[0],
        (const float*)d_in[1], (const float*)d_in[3], (const float*)d_in[5], (const float*)d_in[7],
        (const float*)d_in[2], (const float*)d_in[4], (const float*)d_in[6], (const float*)d_in[8],
        xp, WTp, biasf);
  } else {
    prep<u16><<<5120, blk, 0, stream>>>(
        (const u16*)d_in[0],
        (const u16*)d_in[1], (const u16*)d_in[3], (const u16*)d_in[5], (const u16*)d_in[7],
        (const u16*)d_in[2], (const u16*)d_in[4], (const u16*)d_in[6], (const u16*)d_in[8],
        xp, WTp, biasf);
  }
  qkv_gemm<<<dim3(128, 4), blk, 0, stream>>>(xp, WTp, biasf, Qw, Kw, VTg);
  attn<<<dim3(16, 32), blk, 0, stream>>>(Qw, Kw, VTg, ctxp);
  if (f32in) out_gemm<false><<<dim3(128, 2), blk, 0, stream>>>(ctxp, WTp, biasf + 3 * 256, d_out);
  else       out_gemm<true ><<<dim3(128, 2), blk, 0, stream>>>(ctxp, WTp, biasf + 3 * 256, d_out);
}

// Round 12
// 137.053 us; speedup vs baseline: 1.0409x; 1.0409x over previous
//
#include <hip/hip_runtime.h>

// MultiHeadAttention: B=8, S=2048, D=256, H=4, hd=64
// R16: attn = R15 exactly (R12 pipeline + v_perm pack_trunc; 43.2us best).
//      qkv: Q/K stores reverted to R12 scalar path (R15's LDS-transpose stores
//      regressed ~5us) + A staged DIRECTLY from x (reg-stage f32 -> pack_rne ->
//      swizzled ds_write_b128; per-block rows are self-contained so no
//      cross-block dep) -> prep's x-pass eliminated (5120->1024 blocks,
//      weights+bias only): saves 24MB traffic + one launch gap.
// R12: T4 counted-vmcnt triple-buffer + T5 setprio.
// R6: P-in-register via K-row permutation pi(s)=(s&0x20)|((s&0x0C)<<1)|
//     ((s&0x10)>>2)|(s&3); raw v_exp_f32; fixed-exponent softmax (exact).
// Known fixed costs in dur_us: harness fillBuffer ~45us (workspace zero).
// MFMA layouts (m89/m91 HW-verified):
//   A-frag: lane holds A[m=lane&15][k=(lane>>4)*8+j]
//   B-frag: lane holds B[k=(lane>>4)*8+j][n=lane&15]
//   C/D:    lane,reg holds D[row=(lane>>4)*4+reg][col=lane&15]

typedef unsigned short u16;
typedef __bf16 bf16x8 __attribute__((ext_vector_type(8)));
typedef float  f32x4  __attribute__((ext_vector_type(4)));
typedef unsigned int u32x4 __attribute__((ext_vector_type(4)));
typedef unsigned int u32x2 __attribute__((ext_vector_type(2)));

#define LOG2E   1.4426950408889634f
#define ATTN_SC (0.125f * LOG2E)    // 1/sqrt(64) * log2(e), folded into Q
#define PSTR    2097152             // 16384*128: one K-panel of ctx (elements)
#define WPSTR   32768               // 256*128: one K-panel of W^T
#define WZSTR   65536               // per weight matrix (2 panels)

__device__ __forceinline__ u16 f2b(float f) {            // fp32 -> bf16 RNE
  unsigned u = __builtin_bit_cast(unsigned, f);
  u += 0x7FFFu + ((u >> 16) & 1u);
  return (u16)(u >> 16);
}
__device__ __forceinline__ float b2f(u16 b) {
  return __builtin_bit_cast(float, (unsigned)b << 16);
}
// dst = {b[31:16], a[31:16]}: one v_perm_b32 (S0=b -> bytes 4-7, S1=a -> bytes 0-3)
__device__ __forceinline__ unsigned pack_trunc(float a, float b) {
  return __builtin_amdgcn_perm(__builtin_bit_cast(unsigned, b),
                               __builtin_bit_cast(unsigned, a), 0x07060302u);
}
__device__ __forceinline__ unsigned pack_rne(float a, float b) {
  return (unsigned)f2b(a) | ((unsigned)f2b(b) << 16);
}
__device__ __forceinline__ f32x4 mfma16(bf16x8 a, bf16x8 b, f32x4 c) {
  return __builtin_amdgcn_mfma_f32_16x16x32_bf16(a, b, c, 0, 0, 0);
}
// async global->LDS, 16B/lane; LDS dest = wave-uniform base + lane*16
__device__ __forceinline__ void cp16(const u16* g, u16* l) {
  __builtin_amdgcn_global_load_lds((const __attribute__((address_space(1))) void*)g,
                                   (__attribute__((address_space(3))) void*)l, 16, 0, 0);
}

// ---------------- prep: W transpose panel-major + biases (weights only) ----------------
template <typename T>
__global__ __launch_bounds__(256) void prep(const T* __restrict__ W0, const T* __restrict__ W1,
                                            const T* __restrict__ W2, const T* __restrict__ W3,
                                            const T* __restrict__ b0, const T* __restrict__ b1,
                                            const T* __restrict__ b2, const T* __restrict__ b3,
                                            u16* __restrict__ WTp, float* __restrict__ biasf) {
  int bid = blockIdx.x;                                  // 1024 blocks
  const int z = bid >> 8;
  const T* W = z == 0 ? W0 : z == 1 ? W1 : z == 2 ? W2 : W3;
  const T* b = z == 0 ? b0 : z == 1 ? b1 : z == 2 ? b2 : b3;
  int idx = (bid & 255) * 256 + threadIdx.x;
  int k = idx >> 8, n = idx & 255;
  u16 wb;
  if constexpr (sizeof(T) == 4) wb = f2b((float)W[k * 256 + n]);
  else                          wb = (u16)W[k * 256 + n];
  WTp[z * WZSTR + (k >> 7) * WPSTR + n * 128 + (k & 127)] = wb;
  if (idx < 256) {
    float bv;
    if constexpr (sizeof(T) == 4) bv = (float)b[idx];
    else                          bv = b2f((u16)b[idx]);
    biasf[z * 256 + idx] = bv;
  }
}

// ---------------- QKV projection, z-fused: 128 rows x 64 cols x {Q,K,V} ----------------
// A staged directly from x (row-major [16384][256]) with on-the-fly bf16
// conversion; LDS swizzle: logical 16B-chunk c of row r at physical chunk
// c^(r&15) (same layout the compute loop expects).
template <typename T>
__global__ __launch_bounds__(256, 2) void qkv_gemm(const T* __restrict__ x, const u16* __restrict__ WTp,
                                                   const float* __restrict__ biasf,
                                                   u16* __restrict__ Qw, u16* __restrict__ Kw,
                                                   u16* __restrict__ VTg) {
  __shared__ __align__(16) u16 Al[128 * 128];            // 32 KB
  __shared__ __align__(16) u16 Bl[3][64 * 128];          // 48 KB
  const int tid = threadIdx.x, w = tid >> 6, lane = tid & 63;
  const int l16 = lane & 15, quad = lane >> 4;
  const int n0 = blockIdx.y * 64, m0 = blockIdx.x * 128;
  f32x4 acc[3][2][4];
#pragma unroll
  for (int z = 0; z < 3; ++z)
#pragma unroll
    for (int mm = 0; mm < 2; ++mm)
#pragma unroll
      for (int nb = 0; nb < 4; ++nb) acc[z][mm][nb] = (f32x4){0.f, 0.f, 0.f, 0.f};

#pragma unroll
  for (int p = 0; p < 2; ++p) {
    __syncthreads();
    // ---- A: reg-stage from x, convert, swizzled ds_write (128x128 bf16 tile)
    const T* Ax = x + (size_t)m0 * 256 + p * 128;
#pragma unroll
    for (int i = 0; i < 8; ++i) {
      int slot = i * 256 + tid;
      int row = slot >> 4, pc = slot & 15, c = pc ^ (row & 15);
      u32x4 dv;
      if constexpr (sizeof(T) == 4) {
        const float* src = (const float*)Ax + (size_t)row * 256 + c * 8;
        f32x4 a = *(const f32x4*)src;
        f32x4 b = *(const f32x4*)(src + 4);
        dv = (u32x4){pack_rne(a[0], a[1]), pack_rne(a[2], a[3]),
                     pack_rne(b[0], b[1]), pack_rne(b[2], b[3])};
      } else {
        dv = *(const u32x4*)((const u16*)Ax + (size_t)row * 256 + c * 8);
      }
      *(u32x4*)&Al[(row * 16 + pc) * 8] = dv;
    }
    // ---- B[z]: async global->LDS (unchanged)
#pragma unroll
    for (int z = 0; z < 3; ++z) {                 // B[z]: 64x128 = 1024 chunks each
      const u16* Bp = WTp + z * WZSTR + n0 * 128 + p * WPSTR;
#pragma unroll
      for (int i = 0; i < 4; ++i) {
        int slot = i * 256 + w * 64 + lane;
        int row = slot >> 4, pc = slot & 15, c = pc ^ (row & 15);
        cp16(Bp + (size_t)row * 128 + c * 8, Bl[z] + (i * 256 + w * 64) * 8);
      }
    }
    __syncthreads();
#pragma unroll
    for (int kc = 0; kc < 4; ++kc) {
      bf16x8 a0 = *(const bf16x8*)&Al[(w * 32 + l16) * 128 + (((kc * 4 + quad) ^ l16)) * 8];
      bf16x8 a1 = *(const bf16x8*)&Al[(w * 32 + 16 + l16) * 128 + (((kc * 4 + quad) ^ l16)) * 8];
#pragma unroll
      for (int z = 0; z < 3; ++z)
#pragma unroll
        for (int nb = 0; nb < 4; ++nb) {
          bf16x8 b = *(const bf16x8*)&Bl[z][(nb * 16 + l16) * 128 + (((kc * 4 + quad) ^ l16)) * 8];
          acc[z][0][nb] = mfma16(a0, b, acc[z][0][nb]);
          acc[z][1][nb] = mfma16(a1, b, acc[z][1][nb]);
        }
    }
  }

  const int bb = m0 >> 11, s0 = m0 & 2047, h = blockIdx.y;
  // ---- Q (scaled) and K stores (R12 scalar path - proven)
#pragma unroll
  for (int z = 0; z < 2; ++z) {
    u16* dst = (z == 0) ? Qw : Kw;
    const float sc = (z == 0) ? ATTN_SC : 1.0f;
    const float* bp = biasf + z * 256;
#pragma unroll
    for (int mm = 0; mm < 2; ++mm)
#pragma unroll
      for (int nb = 0; nb < 4; ++nb) {
        int d = nb * 16 + l16;
        float bv = bp[n0 + d];
#pragma unroll
        for (int r = 0; r < 4; ++r) {
          int s = s0 + w * 32 + mm * 16 + quad * 4 + r;
          dst[(((size_t)(bb * 4 + h) * 2048) + s) * 64 + d] = f2b((acc[z][mm][nb][r] + bv) * sc);
        }
      }
  }
  // ---- V: transpose 128(s) x 64(d) tile through Bl[0] (swizzled [d][s]), store V^T coalesced
  __syncthreads();
  {
    const float* bp = biasf + 2 * 256;
#pragma unroll
    for (int mm = 0; mm < 2; ++mm)
#pragma unroll
      for (int nb = 0; nb < 4; ++nb) {
        int d = nb * 16 + l16;
        float bv = bp[n0 + d];
        f32x4 v = acc[2][mm][nb];
        u32x2 dd = { pack_rne(v[0] + bv, v[1] + bv), pack_rne(v[2] + bv, v[3] + bv) };
        int cch = w * 4 + mm * 2 + (quad >> 1);
        *(u32x2*)&Bl[0][d * 128 + ((cch ^ (d & 15))) * 8 + (quad & 1) * 4] = dd;
      }
    __syncthreads();
#pragma unroll
    for (int i = 0; i < 4; ++i) {
      int slot = i * 256 + tid;
      int d = slot >> 4, pc = slot & 15;
      u32x4 vv = *(const u32x4*)&Bl[0][d * 128 + ((pc ^ (d & 15))) * 8];
      *(u32x4*)(VTg + (((size_t)(bb * 4 + h) * 64) + d) * 2048 + s0 + pc * 8) = vv;
    }
  }
}

// ---------------- output projection: 128 x 128 tiles ----------------
template <bool OUT_BF16>
__global__ __launch_bounds__(256, 2) void out_gemm(const u16* __restrict__ ctxp, const u16* __restrict__ WTp,
                                                   const float* __restrict__ bo, void* __restrict__ outv) {
  __shared__ __align__(16) u16 Al[128 * 128];            // 32 KB
  __shared__ __align__(16) u16 Bl[128 * 128];            // 32 KB
  const int tid = threadIdx.x, w = tid >> 6, lane = tid & 63;
  const int l16 = lane & 15, quad = lane >> 4;
  const int n0 = blockIdx.y * 128, m0 = blockIdx.x * 128;
  f32x4 acc[2][8];
#pragma unroll
  for (int mm = 0; mm < 2; ++mm)
#pragma unroll
    for (int nb = 0; nb < 8; ++nb) acc[mm][nb] = (f32x4){0.f, 0.f, 0.f, 0.f};

#pragma unroll
  for (int p = 0; p < 2; ++p) {
    __syncthreads();
    const u16* Ap = ctxp + (size_t)m0 * 128 + (size_t)p * PSTR;
    const u16* Bp = WTp + 3 * WZSTR + n0 * 128 + p * WPSTR;
#pragma unroll
    for (int i = 0; i < 8; ++i) {                 // A: 128x128 = 2048 chunks
      int slot = i * 256 + w * 64 + lane;
      int row = slot >> 4, pc = slot & 15, c = pc ^ (row & 15);
      cp16(Ap + (size_t)row * 128 + c * 8, Al + (i * 256 + w * 64) * 8);
    }
#pragma unroll
    for (int i = 0; i < 8; ++i) {                 // B: 128x128 = 2048 chunks
      int slot = i * 256 + w * 64 + lane;
      int row = slot >> 4, pc = slot & 15, c = pc ^ (row & 15);
      cp16(Bp + (size_t)row * 128 + c * 8, Bl + (i * 256 + w * 64) * 8);
    }
    __syncthreads();
#pragma unroll
    for (int kc = 0; kc < 4; ++kc) {
      bf16x8 a0 = *(const bf16x8*)&Al[(w * 32 + l16) * 128 + (((kc * 4 + quad) ^ l16)) * 8];
      bf16x8 a1 = *(const bf16x8*)&Al[(w * 32 + 16 + l16) * 128 + (((kc * 4 + quad) ^ l16)) * 8];
#pragma unroll
      for (int nb = 0; nb < 8; ++nb) {
        bf16x8 b = *(const bf16x8*)&Bl[(nb * 16 + l16) * 128 + (((kc * 4 + quad) ^ l16)) * 8];
        acc[0][nb] = mfma16(a0, b, acc[0][nb]);
        acc[1][nb] = mfma16(a1, b, acc[1][nb]);
      }
    }
  }

#pragma unroll
  for (int mm = 0; mm < 2; ++mm)
#pragma unroll
    for (int nb = 0; nb < 8; ++nb) {
      int n = n0 + nb * 16 + l16;
      float bv = bo[n];
#pragma unroll
      for (int r = 0; r < 4; ++r) {
        size_t m = m0 + w * 32 + mm * 16 + quad * 4 + r;
        float v = acc[mm][nb][r] + bv;
        if constexpr (OUT_BF16) ((u16*)outv)[m * 256 + n] = f2b(v);
        else                    ((float*)outv)[m * 256 + n] = v;
      }
    }
}

// ---------------- fused flash attention: counted-vmcnt triple-buffer (R12/R15) ----------------
// grid (16 q-tiles of 128, 32 bh), block 256; wave w owns q rows [q0+32w, +32)
// as two 16-row halves. K rows staged permuted by pi so P stays in-lane.
// Pipeline: STAGE(kt+2) in flight; top-of-loop waits vmcnt(4) = drain only the
// 2-old stage, never the in-flight one (T4). setprio around MFMA (T5).
__global__ __launch_bounds__(256, 2) void attn(const u16* __restrict__ Q, const u16* __restrict__ K,
                                               const u16* __restrict__ VT, u16* __restrict__ ctxp) {
  __shared__ __align__(16) u16 Kt[3][64 * 64];     // [key-slot][d], XOR-swizzled, rows pi-permuted
  __shared__ __align__(16) u16 VTt[3][64 * 64];    // [d][key], natural
  __shared__ __align__(16) u16 Pt[4][16 * 64];     // per-wave epilogue transpose only
  const int tid = threadIdx.x;
  const int w = tid >> 6, lane = tid & 63;
  const int l16 = lane & 15, quad = lane >> 4;
  const int bh = blockIdx.y, q0 = blockIdx.x * 128;
  const u16* Qp = Q + (size_t)bh * 2048 * 64;
  const u16* Kp = K + (size_t)bh * 2048 * 64;
  const u16* Vp = VT + (size_t)bh * 64 * 2048;     // [d][s]
  u16* Ptw = Pt[w];

  bf16x8 qf[2][2];                                 // [half][kc]
#pragma unroll
  for (int h = 0; h < 2; ++h) {
    int qrow = q0 + w * 32 + h * 16 + l16;
    qf[h][0] = *(const bf16x8*)(Qp + (size_t)qrow * 64 + quad * 8);
    qf[h][1] = *(const bf16x8*)(Qp + (size_t)qrow * 64 + 32 + quad * 8);
  }

  f32x4 acc[2][4];                                 // [half][nbD]
#pragma unroll
  for (int h = 0; h < 2; ++h)
#pragma unroll
    for (int nb = 0; nb < 4; ++nb) acc[h][nb] = (f32x4){0.f, 0.f, 0.f, 0.f};
  float dn0 = 0.f, dn1 = 0.f;                      // per-lane denom partials

  // staging geometry: 512 chunk-slots/tensor/tile, 2 per thread; chunk swizzle ^(ldsrow&7)
  const int sl0 = w * 64 + lane, sl1 = 256 + w * 64 + lane;
  const int r0 = sl0 >> 3, c0 = (sl0 & 7) ^ (r0 & 7);
  const int r1 = sl1 >> 3, c1 = (sl1 & 7) ^ (r1 & 7);
  // K row permutation: LDS row s holds global key row pi(s)
  const int pr0 = (r0 & 0x20) | ((r0 & 0x0C) << 1) | ((r0 & 0x10) >> 2) | (r0 & 3);
  const int pr1 = (r1 & 0x20) | ((r1 & 0x0C) << 1) | ((r1 & 0x10) >> 2) | (r1 & 3);

#define STAGE(kt_, KB_, VB_)                                                        \
  do {                                                                              \
    cp16(Kp + (size_t)((kt_) * 64 + pr0) * 64 + c0 * 8, (KB_) + (w * 64) * 8);      \
    cp16(Kp + (size_t)((kt_) * 64 + pr1) * 64 + c1 * 8, (KB_) + (256 + w * 64) * 8);\
    cp16(Vp + (size_t)r0 * 2048 + (kt_) * 64 + c0 * 8, (VB_) + (w * 64) * 8);       \
    cp16(Vp + (size_t)r1 * 2048 + (kt_) * 64 + c1 * 8, (VB_) + (256 + w * 64) * 8); \
  } while (0)

  u16 *Ka = Kt[0], *Kb = Kt[1], *Kc = Kt[2];
  u16 *Va = VTt[0], *Vb = VTt[1], *Vc = VTt[2];
  STAGE(0, Ka, Va);
  STAGE(1, Kb, Vb);

  for (int kt = 0; kt < 32; ++kt) {
    // drain only the stage for THIS tile (issued 2 iterations ago); keep the
    // next stage (4 cp16/thread) in flight across the barrier (T4).
    if (kt == 31) __builtin_amdgcn_s_waitcnt(0x0F70);   // vmcnt(0): last tile
    else          __builtin_amdgcn_s_waitcnt(0x0F74);   // vmcnt(4)
    __asm__ __volatile__("" ::: "memory");
    __builtin_amdgcn_s_barrier();                  // raw barrier: no compiler drain
    __asm__ __volatile__("" ::: "memory");
    if (kt < 30) STAGE(kt + 2, Kc, Vc);            // 2-ahead prefetch

    const u16* KtB = Ka;
    const u16* VtB = Va;

    // hoist K-frags + V-frags once; both q-halves reuse them
    bf16x8 kfr[2][4];                              // [kc][nbK]
#pragma unroll
    for (int kc = 0; kc < 2; ++kc)
#pragma unroll
      for (int nbK = 0; nbK < 4; ++nbK)
        kfr[kc][nbK] = *(const bf16x8*)&KtB[(nbK * 16 + l16) * 64 + (((kc * 4 + quad) ^ (l16 & 7))) * 8];
    bf16x8 vbr[2][4];                              // [m][nbD]
#pragma unroll
    for (int m = 0; m < 2; ++m)
#pragma unroll
      for (int nbD = 0; nbD < 4; ++nbD)
        vbr[m][nbD] = *(const bf16x8*)&VtB[(nbD * 16 + l16) * 64 + (((m * 4 + quad) ^ (l16 & 7))) * 8];

#pragma unroll
    for (int h = 0; h < 2; ++h) {
      // S^T = K * Q^T : lane holds st[key-slot = nbK*16+quad*4+r][q=l16]
      f32x4 st[4];
#pragma unroll
      for (int nb = 0; nb < 4; ++nb) st[nb] = (f32x4){0.f, 0.f, 0.f, 0.f};
      __builtin_amdgcn_s_setprio(1);
#pragma unroll
      for (int kc = 0; kc < 2; ++kc)
#pragma unroll
        for (int nbK = 0; nbK < 4; ++nbK)
          st[nbK] = mfma16(kfr[kc][nbK], qf[h][kc], st[nbK]);
      __builtin_amdgcn_s_setprio(0);

      // P = exp2(st), packed in-lane: thanks to pi, word order IS the PV B-frag
      unsigned pw[8];
      float d = 0.f;
#pragma unroll
      for (int nbK = 0; nbK < 4; ++nbK) {
        float p0 = __builtin_amdgcn_exp2f(st[nbK][0]);
        float p1 = __builtin_amdgcn_exp2f(st[nbK][1]);
        float p2 = __builtin_amdgcn_exp2f(st[nbK][2]);
        float p3 = __builtin_amdgcn_exp2f(st[nbK][3]);
        d += (p0 + p1) + (p2 + p3);
        pw[nbK * 2]     = pack_trunc(p0, p1);
        pw[nbK * 2 + 1] = pack_trunc(p2, p3);
      }
      if (h == 0) dn0 += d; else dn1 += d;
      bf16x8 pb0 = __builtin_bit_cast(bf16x8, (u32x4){pw[0], pw[1], pw[2], pw[3]});
      bf16x8 pb1 = __builtin_bit_cast(bf16x8, (u32x4){pw[4], pw[5], pw[6], pw[7]});

      // ctx^T += V^T * P^T
      __builtin_amdgcn_s_setprio(1);
#pragma unroll
      for (int nbD = 0; nbD < 4; ++nbD) acc[h][nbD] = mfma16(vbr[0][nbD], pb0, acc[h][nbD]);
#pragma unroll
      for (int nbD = 0; nbD < 4; ++nbD) acc[h][nbD] = mfma16(vbr[1][nbD], pb1, acc[h][nbD]);
      __builtin_amdgcn_s_setprio(0);
    }

    // rotate triple buffers (uniform pointer moves)
    u16* t;
    t = Ka; Ka = Kb; Kb = Kc; Kc = t;
    t = Va; Va = Vb; Vb = Vc; Vc = t;
  }
#undef STAGE

  // denom: reduce across the 4 quads sharing q=l16
  float linv0, linv1;
  { float d = dn0; d += __shfl_xor(d, 16); d += __shfl_xor(d, 32); linv0 = 1.0f / d; }
  { float d = dn1; d += __shfl_xor(d, 16); d += __shfl_xor(d, 32); linv1 = 1.0f / d; }

  // epilogue: normalize, transpose via wave-private Ptw, b128 panel-major stores
  const int bb = bh >> 2, hh = bh & 3;
  const int p = hh >> 1, pcol = (hh & 1) * 64;
#pragma unroll
  for (int h = 0; h < 2; ++h) {
    const float linv = h ? linv1 : linv0;
#pragma unroll
    for (int nbD = 0; nbD < 4; ++nbD) {
      f32x4 v = acc[h][nbD];
      u32x2 dd = { pack_rne(v[0] * linv, v[1] * linv), pack_rne(v[2] * linv, v[3] * linv) };
      int cch = nbD * 2 + (quad >> 1);
      *(u32x2*)&Ptw[l16 * 64 + ((cch ^ (l16 & 7))) * 8 + (quad & 1) * 4] = dd;
    }
    __asm__ __volatile__("" ::: "memory");
#pragma unroll
    for (int cc2 = 0; cc2 < 2; ++cc2) {
      int slot = cc2 * 64 + lane;                  // 16 q-rows x 8 chunks
      int row = slot >> 3, pc = slot & 7;
      u32x4 vv = *(const u32x4*)&Ptw[row * 64 + ((pc ^ (row & 7))) * 8];
      size_t m = (size_t)bb * 2048 + q0 + w * 32 + h * 16 + row;
      *(u32x4*)&ctxp[(size_t)p * PSTR + m * 128 + pcol + pc * 8] = vv;
    }
    __asm__ __volatile__("" ::: "memory");
  }
}

// ---------------- host ----------------
extern "C" void kernel_launch(void* const* d_in, const int* in_sizes, int n_in,
                              void* d_out, int out_size, void* d_ws, size_t ws_size,
                              hipStream_t stream) {
  bool f32in = true;
  {
    void* basep = nullptr; size_t sz = 0;
    hipError_t e = hipMemGetAddressRange((hipDeviceptr_t*)&basep, &sz, (hipDeviceptr_t)d_in[0]);
    if (e == hipSuccess && sz > 0) f32in = sz >= (size_t)in_sizes[0] * 4;
    else f32in = false;
  }

  char* ws = (char*)d_ws;
  u16*   ctxp  = (u16*)(ws + 0);          // 8 MB: ctx panel-major [2][16384][128]
  u16*   WTp   = (u16*)(ws + 8388608);    // 512 KB: W^T panel-major [4][2][256][128]
  float* biasf = (float*)(ws + 8912896);  // 4 KB
  u16*   Qw    = (u16*)(ws + 8916992);    // 8 MB [B,H,S,hd], pre-scaled by ATTN_SC
  u16*   Kw    = (u16*)(ws + 17305600);   // 8 MB [B,H,S,hd]
  u16*   VTg   = (u16*)(ws + 25694208);   // 8 MB [B,H,hd,S]

  dim3 blk(256);
  if (f32in) {
    prep<float><<<1024, blk, 0, stream>>>(
        (const float*)d_in[1], (const float*)d_in[3], (const float*)d_in[5], (const float*)d_in[7],
        (const float*)d_in[2], (const float*)d_in[4], (const float*)d_in[6], (const float*)d_in[8],
        WTp, biasf);
    qkv_gemm<float><<<dim3(128, 4), blk, 0, stream>>>((const float*)d_in[0], WTp, biasf, Qw, Kw, VTg);
  } else {
    prep<u16><<<1024, blk, 0, stream>>>(
        (const u16*)d_in[1], (const u16*)d_in[3], (const u16*)d_in[5], (const u16*)d_in[7],
        (const u16*)d_in[2], (const u16*)d_in[4], (const u16*)d_in[6], (const u16*)d_in[8],
        WTp, biasf);
    qkv_gemm<u16><<<dim3(128, 4), blk, 0, stream>>>((const u16*)d_in[0], WTp, biasf, Qw, Kw, VTg);
  }
  attn<<<dim3(16, 32), blk, 0, stream>>>(Qw, Kw, VTg, ctxp);
  if (f32in) out_gemm<false><<<dim3(128, 2), blk, 0, stream>>>(ctxp, WTp, biasf + 3 * 256, d_out);
  else       out_gemm<true ><<<dim3(128, 2), blk, 0, stream>>>(ctxp, WTp, biasf + 3 * 256, d_out);
}